// Round 10
// baseline (287.375 us; speedup 1.0000x reference)
//
#include <hip/hip_runtime.h>

#define N_IN_CH 256
#define N_OUT_CH 64
#define BROW 128      // rows per bucket
#define NBK 1024      // max buckets: ceil(100000/128) = 782
#define B1_T 256      // bin-role threads (= fused block size)
#define B1_PT 16      // edges per bin-role thread
#define B1_E 4096     // edges per bin-role block (256 thr x 16 edges)
#define ECAP 4096     // edges per padded bucket region AND LDS buffer (mean 2048, 45-sigma)
#define OVFCAP 65536  // overflow edge capacity (never hit for uniform rows)
#define NGEMM 512     // gemm-role blocks in the fused kernel

typedef __attribute__((ext_vector_type(8))) short short8;
typedef __attribute__((ext_vector_type(4))) float f32x4;

__device__ inline ushort f2bf(float f) {
    unsigned u = __float_as_uint(f);
    return (ushort)((u + 0x7FFFu + ((u >> 16) & 1u)) >> 16);   // RTNE
}
__device__ inline float bf2f(ushort u) {
    return __uint_as_float(((unsigned)u) << 16);
}

// --- Fused GEMM | bin kernel.
//     R9 post-mortem: 140 VGPR -> 12 waves/CU strangled BOTH roles (fusion of
//     two latency-bound roles gains nothing when waves/CU is the shared cap).
//     GEMM role rebuilt: kt-outer loop, per-kt convert-then-refill of raw[2kt]
//     (16-deep prefetch kept, a[8] eliminated, 4 persistent acc chains);
//     launch_bounds(256,4) enforces <=128 VGPR -> 16 waves/CU.
//     Ws: exactly 32 KB, XOR-swizzled (byte ^= (row&7)<<4) on store AND load.
//     Bin role: 16 edges/thread (segments 2.6 -> 5.2 edges: less write amp). ---
__global__ __launch_bounds__(256, 4) void fused_kernel(const float* __restrict__ X,
        const float* __restrict__ W, ushort* __restrict__ Xp, int nrows, int ngemm,
        const int* __restrict__ rows, const int* __restrict__ cols,
        const float* __restrict__ vals, int* __restrict__ bcur,
        int* __restrict__ ovfcnt, int4* __restrict__ ovf,
        int2* __restrict__ colbuf, int nnz, int nb) {
    __shared__ union SM {
        ushort ws[64 * 256];                       // 32 KB (gemm role, swizzled)
        struct { int cnt[NBK]; int base[NBK]; } b; // 8 KB (bin role)
    } sm;
    const int tid = threadIdx.x;

    if (blockIdx.x < ngemm) {
        // ================= GEMM role =================
        // stage W fp32 -> bf16 into swizzled LDS: row n, byte col x stored at
        // n*512 + (x ^ ((n&7)<<4))
        #pragma unroll
        for (int it = 0; it < 16; ++it) {
            int f = it * 256 + tid;
            int n = f >> 6, c4 = f & 63;
            float4 w = *(const float4*)&W[n * N_IN_CH + c4 * 4];
            ushort4 u;
            u.x = f2bf(w.x); u.y = f2bf(w.y); u.z = f2bf(w.z); u.w = f2bf(w.w);
            int byteoff = (n << 9) | (((c4 << 3)) ^ ((n & 7) << 4));
            *(ushort4*)((char*)sm.ws + byteoff) = u;
        }
        __syncthreads();

        const int wave = tid >> 6, lane = tid & 63;
        const int ml = lane & 15, q = lane >> 4;
        const int swz = (ml & 7) << 4;
        const int q16 = q << 4;
        const int ntiles = (nrows + 15) >> 4;
        const int nw = ngemm * 4;
        int t = blockIdx.x * 4 + wave;

        const char* wsb = (const char*)sm.ws;
        float4 raw[16];

        // prologue: full 16-load prefetch of the first tile
        if (t < ntiles) {
            int gr0 = t * 16 + ml;
            if (gr0 < nrows) {
                const float* xr = X + (size_t)gr0 * N_IN_CH + q * 8;
                #pragma unroll
                for (int kt = 0; kt < 8; ++kt) {
                    raw[2 * kt]     = *(const float4*)&xr[kt * 32];
                    raw[2 * kt + 1] = *(const float4*)&xr[kt * 32 + 4];
                }
            } else {
                #pragma unroll
                for (int i = 0; i < 16; ++i) raw[i] = make_float4(0.f, 0.f, 0.f, 0.f);
            }
        }

        while (t < ntiles) {
            const int tn = t + nw;
            const int grn = tn * 16 + ml;
            const bool okn = grn < nrows;
            const float* xrn = X + (size_t)grn * N_IN_CH + q * 8;

            f32x4 acc[4];
            #pragma unroll
            for (int nt = 0; nt < 4; ++nt) acc[nt] = (f32x4){0.f, 0.f, 0.f, 0.f};

            #pragma unroll
            for (int kt = 0; kt < 8; ++kt) {
                // convert this kt-slice (raw dies here)
                float4 f0 = raw[2 * kt], f1 = raw[2 * kt + 1];
                short8 s;
                s[0] = (short)f2bf(f0.x); s[1] = (short)f2bf(f0.y);
                s[2] = (short)f2bf(f0.z); s[3] = (short)f2bf(f0.w);
                s[4] = (short)f2bf(f1.x); s[5] = (short)f2bf(f1.y);
                s[6] = (short)f2bf(f1.z); s[7] = (short)f2bf(f1.w);
                // refill with next tile's kt-slice (in flight across ~7/8 of
                // this tile's compute)
                if (tn < ntiles) {
                    if (okn) {
                        raw[2 * kt]     = *(const float4*)&xrn[kt * 32];
                        raw[2 * kt + 1] = *(const float4*)&xrn[kt * 32 + 4];
                    } else {
                        raw[2 * kt]     = make_float4(0.f, 0.f, 0.f, 0.f);
                        raw[2 * kt + 1] = make_float4(0.f, 0.f, 0.f, 0.f);
                    }
                }
                // 4 MFMAs on swizzled LDS B-frags: row nt*16+ml, byte col
                // kt*64 + q*16, XOR swz
                #pragma unroll
                for (int nt = 0; nt < 4; ++nt) {
                    short8 b = *(const short8*)(wsb + ((nt * 16 + ml) << 9)
                                                + (((kt << 6) | q16) ^ swz));
                    acc[nt] = __builtin_amdgcn_mfma_f32_16x16x32_bf16(s, b, acc[nt], 0, 0, 0);
                }
            }

            // C/D: col = lane&15 (n in tile), row = q*4+reg (m in tile)
            #pragma unroll
            for (int nt = 0; nt < 4; ++nt) {
                #pragma unroll
                for (int reg = 0; reg < 4; ++reg) {
                    int gr = t * 16 + q * 4 + reg;
                    if (gr < nrows)
                        Xp[(size_t)gr * N_OUT_CH + nt * 16 + ml] = f2bf(acc[nt][reg]);
                }
            }
            t = tn;
        }
    } else {
        // ================= bin role =================
        for (int i = tid; i < nb; i += B1_T) sm.b.cnt[i] = 0;
        __syncthreads();

        const int e = (blockIdx.x - ngemm) * B1_E + tid * B1_PT;
        int nval = nnz - e;
        if (nval > B1_PT) nval = B1_PT;
        if (nval < 0) nval = 0;

        int r[B1_PT], c[B1_PT]; float v[B1_PT];
        if (nval == B1_PT) {
            #pragma unroll
            for (int j = 0; j < B1_PT / 4; ++j) {
                *(int4*)&r[4 * j] = *(const int4*)&rows[e + 4 * j];
                *(int4*)&c[4 * j] = *(const int4*)&cols[e + 4 * j];
                *(float4*)&v[4 * j] = *(const float4*)&vals[e + 4 * j];
            }
        } else {
            #pragma unroll
            for (int j = 0; j < B1_PT; ++j)
                if (j < nval) { r[j] = rows[e + j]; c[j] = cols[e + j]; v[j] = vals[e + j]; }
        }

        #pragma unroll
        for (int j = 0; j < B1_PT; ++j)
            if (j < nval) atomicAdd(&sm.b.cnt[r[j] >> 7], 1);
        __syncthreads();

        for (int i = tid; i < nb; i += B1_T) {
            int cn = sm.b.cnt[i];
            sm.b.base[i] = cn ? atomicAdd(&bcur[i], cn) : 0;
            sm.b.cnt[i] = 0;
        }
        __syncthreads();

        #pragma unroll
        for (int j = 0; j < B1_PT; ++j) {
            if (j < nval) {
                int b = r[j] >> 7;
                int pib = sm.b.base[b] + atomicAdd(&sm.b.cnt[b], 1);
                if (pib < ECAP) {
                    int2 cv;
                    cv.x = c[j] | ((r[j] & 127) << 17);   // col < 2^17, row_local 7b
                    cv.y = __float_as_int(v[j]);
                    colbuf[(size_t)b * ECAP + pib] = cv;
                } else {
                    int op = atomicAdd(ovfcnt, 1);
                    if (op < OVFCAP) {
                        int4 o; o.x = r[j]; o.y = c[j];
                        o.z = __float_as_int(v[j]); o.w = 0;
                        ovf[op] = o;
                    }
                }
            }
        }
    }
}

// --- Fused bucket sort + SpMM. Sort phase: register chunks, int LDS atomics
//     (float LDS atomics are a CAS loop, 10x slower, measured R2), sorted
//     32 KB ebuf. Consume: quarter-wave (16 lanes) per edge, lane = 4
//     channels (ushort4), 8-deep gather batches (R9: 4-deep under-hid the
//     ~40% L3-miss HBM latency on the random 128 B row gathers). ---
__global__ __launch_bounds__(512) void bspmm_kernel(const int* __restrict__ bcur,
        const int2* __restrict__ colbuf, const ushort* __restrict__ Xp,
        float* __restrict__ out, int nrows, const int* __restrict__ ovfcnt,
        const int4* __restrict__ ovf) {
    __shared__ int2 ebuf[ECAP];       // 32 KB
    __shared__ int rc[BROW];
    __shared__ int rb[BROW + 1];
    const int b = blockIdx.x, t = threadIdx.x;
    const int ne = min(bcur[b], ECAP);
    const int2* cb = colbuf + (size_t)b * ECAP;
    const int row0 = b * BROW;

    // ---- sort phase ----
    int2 ev[8];
    const int ebase = t * 8;
    int ecnt = ne - ebase;
    if (ecnt > 8) ecnt = 8;
    if (ecnt < 0) ecnt = 0;
    if (ecnt == 8) {
        #pragma unroll
        for (int j = 0; j < 4; ++j)
            *(int4*)&ev[2 * j] = *(const int4*)&cb[ebase + 2 * j];
    } else {
        #pragma unroll
        for (int j = 0; j < 8; ++j)
            if (j < ecnt) ev[j] = cb[ebase + j];
    }

    if (t < BROW) rc[t] = 0;
    __syncthreads();
    #pragma unroll
    for (int j = 0; j < 8; ++j)
        if (j < ecnt) atomicAdd(&rc[(ev[j].x >> 17) & (BROW - 1)], 1);
    __syncthreads();
    int c0 = (t < BROW) ? rc[t] : 0;
    #pragma unroll
    for (int d = 1; d < BROW; d <<= 1) {
        int a = (t < BROW && t >= d) ? rc[t - d] : 0;
        __syncthreads();
        if (t < BROW) rc[t] += a;
        __syncthreads();
    }
    if (t < BROW) rb[t] = rc[t] - c0;
    if (t == 0) rb[BROW] = ne;
    __syncthreads();
    if (t < BROW) rc[t] = 0;
    __syncthreads();
    #pragma unroll
    for (int j = 0; j < 8; ++j) {
        if (j < ecnt) {
            int rl = (ev[j].x >> 17) & (BROW - 1);
            int pos = rb[rl] + atomicAdd(&rc[rl], 1);
            ebuf[pos] = ev[j];
        }
    }
    __syncthreads();

    // ---- consume phase: quarter (16 lanes) per 4-row group, 8-deep ----
    const int wave = t >> 6;
    const int q4 = (t >> 4) & 3;       // quarter within wave
    const int l16 = t & 15;            // lane within quarter; ch = l16*4
    const int qr0 = wave * 16 + q4 * 4;   // first local row of this quarter
    int i = rb[qr0];
    const int e = rb[qr0 + 4];
    float4 acc = make_float4(0.f, 0.f, 0.f, 0.f);
    int cur = -1;

    for (; i + 8 <= e; i += 8) {
        int2 cv[8];
        #pragma unroll
        for (int j = 0; j < 8; ++j) cv[j] = ebuf[i + j];
        ushort4 xv[8];
        #pragma unroll
        for (int j = 0; j < 8; ++j)
            xv[j] = *(const ushort4*)&Xp[(size_t)(cv[j].x & 0x1FFFF) * N_OUT_CH + l16 * 4];
        #pragma unroll
        for (int j = 0; j < 8; ++j) {
            int rl = (cv[j].x >> 17) & (BROW - 1);
            if (rl != cur) {                    // quarter-uniform branch
                if (cur >= 0)
                    *(float4*)&out[(size_t)(row0 + cur) * N_OUT_CH + l16 * 4] = acc;
                cur = rl;
                acc = make_float4(0.f, 0.f, 0.f, 0.f);
            }
            float vv = __int_as_float(cv[j].y);
            acc.x += vv * bf2f(xv[j].x);
            acc.y += vv * bf2f(xv[j].y);
            acc.z += vv * bf2f(xv[j].z);
            acc.w += vv * bf2f(xv[j].w);
        }
    }
    for (; i < e; ++i) {
        int2 cv = ebuf[i];
        int rl = (cv.x >> 17) & (BROW - 1);
        if (rl != cur) {
            if (cur >= 0)
                *(float4*)&out[(size_t)(row0 + cur) * N_OUT_CH + l16 * 4] = acc;
            cur = rl;
            acc = make_float4(0.f, 0.f, 0.f, 0.f);
        }
        ushort4 xv = *(const ushort4*)&Xp[(size_t)(cv.x & 0x1FFFF) * N_OUT_CH + l16 * 4];
        float vv = __int_as_float(cv.y);
        acc.x += vv * bf2f(xv.x);
        acc.y += vv * bf2f(xv.y);
        acc.z += vv * bf2f(xv.z);
        acc.w += vv * bf2f(xv.w);
    }
    if (cur >= 0)
        *(float4*)&out[(size_t)(row0 + cur) * N_OUT_CH + l16 * 4] = acc;

    // zero-fill this quarter's empty rows (rare: P ~ e^-16 per row)
    #pragma unroll
    for (int r = 0; r < 4; ++r) {
        int lr = qr0 + r;
        if (rb[lr] == rb[lr + 1]) {
            int gr = row0 + lr;
            if (gr < nrows)
                *(float4*)&out[(size_t)gr * N_OUT_CH + l16 * 4] =
                    make_float4(0.f, 0.f, 0.f, 0.f);
        }
    }

    // overflow tail: normally n==0 -> one broadcast load + exit
    __syncthreads();
    const int lane = t & 63;
    int n = min(ovfcnt[0], OVFCAP);
    for (int e2 = wave; e2 < n; e2 += 8) {
        int4 v = ovf[e2];
        if ((v.x >> 7) == b)
            atomicAdd(&out[(size_t)v.x * N_OUT_CH + lane],
                      __int_as_float(v.z) * bf2f(Xp[(size_t)v.y * N_OUT_CH + lane]));
    }
}

// --- Fallback atomic SpMM (ws too small — not expected) ---
__global__ __launch_bounds__(256) void spmm_atomic_kernel(const int* __restrict__ rows,
        const int* __restrict__ cols, const float* __restrict__ vals,
        const ushort* __restrict__ Xp, float* __restrict__ out, int nnz) {
    int t = blockIdx.x * blockDim.x + threadIdx.x;
    int e = t >> 6;
    int c = t & 63;
    if (e < nnz) {
        atomicAdd(&out[(size_t)rows[e] * N_OUT_CH + c],
                  vals[e] * bf2f(Xp[(size_t)cols[e] * N_OUT_CH + c]));
    }
}

extern "C" void kernel_launch(void* const* d_in, const int* in_sizes, int n_in,
                              void* d_out, int out_size, void* d_ws, size_t ws_size,
                              hipStream_t stream) {
    const float* X      = (const float*)d_in[2];
    const float* W      = (const float*)d_in[3];
    const int*   L_rows = (const int*)d_in[4];
    const int*   L_cols = (const int*)d_in[5];
    const float* L_vals = (const float*)d_in[6];
    float* out = (float*)d_out;

    const int nrows = in_sizes[2] / N_IN_CH;   // 100000
    const int nnz   = in_sizes[4];             // 1600000
    const int nb    = (nrows + BROW - 1) / BROW;   // 782 buckets

    // workspace layout (16B-aligned blocks)
    size_t off_xp  = 0;
    size_t xp_b    = (size_t)nrows * N_OUT_CH * 2;                   // Xp bf16: 12.8 MB
    size_t off_bc  = off_xp + ((xp_b + 15) & ~(size_t)15);           // bcur[nb] + ovfcnt
    size_t off_ov  = off_bc + (((size_t)(nb + 1) * 4 + 15) & ~(size_t)15);  // ovf int4
    size_t off_cv  = off_ov + (size_t)OVFCAP * 16;                   // colbuf padded
    size_t need    = off_cv + (size_t)nb * ECAP * 8;                 // 25.6 MB

    ushort* Xp = (ushort*)((char*)d_ws + off_xp);
    const bool binned = (ws_size >= need && nb <= NBK);
    int* bcur = (int*)((char*)d_ws + off_bc);

    int ntiles = (nrows + 15) >> 4;
    int ngemm = NGEMM;
    int maxg = (ntiles + 3) / 4;
    if (ngemm > maxg) ngemm = maxg;

    if (binned) {
        int*  ovfcnt = bcur + nb;                          // 1 int
        int4* ovf    = (int4*)((char*)d_ws + off_ov);
        int2* colbuf = (int2*)((char*)d_ws + off_cv);
        int nbin = (nnz + B1_E - 1) / B1_E;

        hipMemsetAsync(bcur, 0, (size_t)(nb + 1) * 4, stream);
        fused_kernel<<<ngemm + nbin, 256, 0, stream>>>(X, W, Xp, nrows, ngemm,
                L_rows, L_cols, L_vals, bcur, ovfcnt, ovf, colbuf, nnz, nb);
        bspmm_kernel<<<nb, 512, 0, stream>>>(bcur, colbuf, Xp, out, nrows, ovfcnt, ovf);
    } else {
        fused_kernel<<<ngemm, 256, 0, stream>>>(X, W, Xp, nrows, ngemm,
                nullptr, nullptr, nullptr, nullptr, nullptr, nullptr, nullptr, 0, 0);
        hipMemsetAsync(d_out, 0, (size_t)out_size * sizeof(float), stream);
        long long total = (long long)nnz * 64;
        spmm_atomic_kernel<<<(int)((total + 255) / 256), 256, 0, stream>>>(
            L_rows, L_cols, L_vals, Xp, out, nnz);
    }
}

// Round 11
// 238.878 us; speedup vs baseline: 1.2030x; 1.2030x over previous
//
#include <hip/hip_runtime.h>

#define N_IN_CH 256
#define N_OUT_CH 64
#define XPAD 264      // 256 + 8 ushort pad: b128 LDS reads spread evenly over banks
#define BROW 128      // rows per bucket
#define NBK 1024      // max buckets: ceil(100000/128) = 782
#define B1_T 256      // bin-role threads (= fused block size)
#define B1_PT 16      // edges per bin-role thread
#define B1_E 4096     // edges per bin-role block (256 thr x 16 edges)
#define ECAP 4096     // edges per padded bucket region AND LDS buffer (mean 2048, 45-sigma)
#define OVFCAP 65536  // overflow edge capacity (never hit for uniform rows)
#define NGEMM 512     // gemm-role blocks in the fused kernel

typedef __attribute__((ext_vector_type(8))) short short8;
typedef __attribute__((ext_vector_type(4))) float f32x4;

__device__ inline ushort f2bf(float f) {
    unsigned u = __float_as_uint(f);
    return (ushort)((u + 0x7FFFu + ((u >> 16) & 1u)) >> 16);   // RTNE
}
__device__ inline float bf2f(ushort u) {
    return __uint_as_float(((unsigned)u) << 16);
}

// --- Fused GEMM | bin kernel.
//     R10 post-mortem: __launch_bounds__(256,4) made the allocator target 64
//     VGPR -> raw[16] and the bin r/c/v[16] spilled to scratch (+150 MB HBM
//     traffic, 70 -> 120 us). REVERTED to R9's register-resident structure
//     (~140 VGPR, 12 waves/CU, zero spill — the lesser evil, measured 70 us).
//     Bin role keeps 16 edges/thread (fits the 140-VGPR envelope; segments
//     5.2 edges -> less colbuf write amplification). ---
__global__ __launch_bounds__(256) void fused_kernel(const float* __restrict__ X,
        const float* __restrict__ W, ushort* __restrict__ Xp, int nrows, int ngemm,
        const int* __restrict__ rows, const int* __restrict__ cols,
        const float* __restrict__ vals, int* __restrict__ bcur,
        int* __restrict__ ovfcnt, int4* __restrict__ ovf,
        int2* __restrict__ colbuf, int nnz, int nb) {
    __shared__ union SM {
        ushort ws[64 * XPAD];                      // 33.8 KB (gemm role)
        struct { int cnt[NBK]; int base[NBK]; } b; // 8 KB (bin role)
    } sm;
    const int tid = threadIdx.x;

    if (blockIdx.x < ngemm) {
        // ================= GEMM role =================
        #pragma unroll
        for (int it = 0; it < 16; ++it) {
            int f = it * 256 + tid;
            int n = f >> 6, c4 = f & 63;
            float4 w = *(const float4*)&W[n * N_IN_CH + c4 * 4];
            ushort4 u;
            u.x = f2bf(w.x); u.y = f2bf(w.y); u.z = f2bf(w.z); u.w = f2bf(w.w);
            *(ushort4*)&sm.ws[n * XPAD + c4 * 4] = u;
        }
        __syncthreads();

        const int wave = tid >> 6, lane = tid & 63;
        const int ml = lane & 15, q = lane >> 4;
        const int ntiles = (nrows + 15) >> 4;
        const int nw = ngemm * 4;
        int t = blockIdx.x * 4 + wave;

        const ushort* wsb = &sm.ws[ml * XPAD + q * 8];

        float4 raw[16];

#define ISSUE_TILE(tt)                                                     \
        do {                                                               \
            int gr_ = (tt) * 16 + ml;                                      \
            if (gr_ < nrows) {                                             \
                const float* xr_ = X + (size_t)gr_ * N_IN_CH + q * 8;      \
                _Pragma("unroll")                                          \
                for (int kt_ = 0; kt_ < 8; ++kt_) {                        \
                    raw[2 * kt_]     = *(const float4*)&xr_[kt_ * 32];     \
                    raw[2 * kt_ + 1] = *(const float4*)&xr_[kt_ * 32 + 4]; \
                }                                                          \
            } else {                                                       \
                _Pragma("unroll")                                          \
                for (int i_ = 0; i_ < 16; ++i_)                            \
                    raw[i_] = make_float4(0.f, 0.f, 0.f, 0.f);             \
            }                                                              \
        } while (0)

        if (t < ntiles) ISSUE_TILE(t);

        while (t < ntiles) {
            short8 a[8];
            #pragma unroll
            for (int kt = 0; kt < 8; ++kt) {
                float4 f0 = raw[2 * kt], f1 = raw[2 * kt + 1];
                short8 s;
                s[0] = (short)f2bf(f0.x); s[1] = (short)f2bf(f0.y);
                s[2] = (short)f2bf(f0.z); s[3] = (short)f2bf(f0.w);
                s[4] = (short)f2bf(f1.x); s[5] = (short)f2bf(f1.y);
                s[6] = (short)f2bf(f1.z); s[7] = (short)f2bf(f1.w);
                a[kt] = s;
            }
            int tn = t + nw;
            if (tn < ntiles) ISSUE_TILE(tn);   // in flight across the compute

            #pragma unroll
            for (int nt = 0; nt < 4; ++nt) {
                f32x4 acc = {0.f, 0.f, 0.f, 0.f};
                #pragma unroll
                for (int kt = 0; kt < 8; ++kt) {
                    short8 b = *(const short8*)&wsb[nt * 16 * XPAD + kt * 32];
                    acc = __builtin_amdgcn_mfma_f32_16x16x32_bf16(a[kt], b, acc, 0, 0, 0);
                }
                // C/D: col = lane&15 (n in tile), row = q*4+reg (m in tile)
                #pragma unroll
                for (int reg = 0; reg < 4; ++reg) {
                    int gr = t * 16 + q * 4 + reg;
                    if (gr < nrows)
                        Xp[(size_t)gr * N_OUT_CH + nt * 16 + ml] = f2bf(acc[reg]);
                }
            }
            t = tn;
        }
#undef ISSUE_TILE
    } else {
        // ================= bin role =================
        for (int i = tid; i < nb; i += B1_T) sm.b.cnt[i] = 0;
        __syncthreads();

        const int e = (blockIdx.x - ngemm) * B1_E + tid * B1_PT;
        int nval = nnz - e;
        if (nval > B1_PT) nval = B1_PT;
        if (nval < 0) nval = 0;

        int r[B1_PT], c[B1_PT]; float v[B1_PT];
        if (nval == B1_PT) {
            #pragma unroll
            for (int j = 0; j < B1_PT / 4; ++j) {
                *(int4*)&r[4 * j] = *(const int4*)&rows[e + 4 * j];
                *(int4*)&c[4 * j] = *(const int4*)&cols[e + 4 * j];
                *(float4*)&v[4 * j] = *(const float4*)&vals[e + 4 * j];
            }
        } else {
            #pragma unroll
            for (int j = 0; j < B1_PT; ++j)
                if (j < nval) { r[j] = rows[e + j]; c[j] = cols[e + j]; v[j] = vals[e + j]; }
        }

        #pragma unroll
        for (int j = 0; j < B1_PT; ++j)
            if (j < nval) atomicAdd(&sm.b.cnt[r[j] >> 7], 1);
        __syncthreads();

        for (int i = tid; i < nb; i += B1_T) {
            int cn = sm.b.cnt[i];
            sm.b.base[i] = cn ? atomicAdd(&bcur[i], cn) : 0;
            sm.b.cnt[i] = 0;
        }
        __syncthreads();

        #pragma unroll
        for (int j = 0; j < B1_PT; ++j) {
            if (j < nval) {
                int b = r[j] >> 7;
                int pib = sm.b.base[b] + atomicAdd(&sm.b.cnt[b], 1);
                if (pib < ECAP) {
                    int2 cv;
                    cv.x = c[j] | ((r[j] & 127) << 17);   // col < 2^17, row_local 7b
                    cv.y = __float_as_int(v[j]);
                    colbuf[(size_t)b * ECAP + pib] = cv;
                } else {
                    int op = atomicAdd(ovfcnt, 1);
                    if (op < OVFCAP) {
                        int4 o; o.x = r[j]; o.y = c[j];
                        o.z = __float_as_int(v[j]); o.w = 0;
                        ovf[op] = o;
                    }
                }
            }
        }
    }
}

// --- Fused bucket sort + SpMM. Sort phase: register chunks, int LDS atomics
//     (float LDS atomics are a CAS loop, 10x slower, measured R2), sorted
//     32 KB ebuf. Consume: quarter-wave (16 lanes) per edge, lane = 4
//     channels (ushort4), 8-deep gather batches. ---
__global__ __launch_bounds__(512) void bspmm_kernel(const int* __restrict__ bcur,
        const int2* __restrict__ colbuf, const ushort* __restrict__ Xp,
        float* __restrict__ out, int nrows, const int* __restrict__ ovfcnt,
        const int4* __restrict__ ovf) {
    __shared__ int2 ebuf[ECAP];       // 32 KB
    __shared__ int rc[BROW];
    __shared__ int rb[BROW + 1];
    const int b = blockIdx.x, t = threadIdx.x;
    const int ne = min(bcur[b], ECAP);
    const int2* cb = colbuf + (size_t)b * ECAP;
    const int row0 = b * BROW;

    // ---- sort phase ----
    int2 ev[8];
    const int ebase = t * 8;
    int ecnt = ne - ebase;
    if (ecnt > 8) ecnt = 8;
    if (ecnt < 0) ecnt = 0;
    if (ecnt == 8) {
        #pragma unroll
        for (int j = 0; j < 4; ++j)
            *(int4*)&ev[2 * j] = *(const int4*)&cb[ebase + 2 * j];
    } else {
        #pragma unroll
        for (int j = 0; j < 8; ++j)
            if (j < ecnt) ev[j] = cb[ebase + j];
    }

    if (t < BROW) rc[t] = 0;
    __syncthreads();
    #pragma unroll
    for (int j = 0; j < 8; ++j)
        if (j < ecnt) atomicAdd(&rc[(ev[j].x >> 17) & (BROW - 1)], 1);
    __syncthreads();
    int c0 = (t < BROW) ? rc[t] : 0;
    #pragma unroll
    for (int d = 1; d < BROW; d <<= 1) {
        int a = (t < BROW && t >= d) ? rc[t - d] : 0;
        __syncthreads();
        if (t < BROW) rc[t] += a;
        __syncthreads();
    }
    if (t < BROW) rb[t] = rc[t] - c0;
    if (t == 0) rb[BROW] = ne;
    __syncthreads();
    if (t < BROW) rc[t] = 0;
    __syncthreads();
    #pragma unroll
    for (int j = 0; j < 8; ++j) {
        if (j < ecnt) {
            int rl = (ev[j].x >> 17) & (BROW - 1);
            int pos = rb[rl] + atomicAdd(&rc[rl], 1);
            ebuf[pos] = ev[j];
        }
    }
    __syncthreads();

    // ---- consume phase: quarter (16 lanes) per 4-row group, 8-deep ----
    const int wave = t >> 6;
    const int q4 = (t >> 4) & 3;       // quarter within wave
    const int l16 = t & 15;            // lane within quarter; ch = l16*4
    const int qr0 = wave * 16 + q4 * 4;   // first local row of this quarter
    int i = rb[qr0];
    const int e = rb[qr0 + 4];
    float4 acc = make_float4(0.f, 0.f, 0.f, 0.f);
    int cur = -1;

    for (; i + 8 <= e; i += 8) {
        int2 cv[8];
        #pragma unroll
        for (int j = 0; j < 8; ++j) cv[j] = ebuf[i + j];
        ushort4 xv[8];
        #pragma unroll
        for (int j = 0; j < 8; ++j)
            xv[j] = *(const ushort4*)&Xp[(size_t)(cv[j].x & 0x1FFFF) * N_OUT_CH + l16 * 4];
        #pragma unroll
        for (int j = 0; j < 8; ++j) {
            int rl = (cv[j].x >> 17) & (BROW - 1);
            if (rl != cur) {                    // quarter-uniform branch
                if (cur >= 0)
                    *(float4*)&out[(size_t)(row0 + cur) * N_OUT_CH + l16 * 4] = acc;
                cur = rl;
                acc = make_float4(0.f, 0.f, 0.f, 0.f);
            }
            float vv = __int_as_float(cv[j].y);
            acc.x += vv * bf2f(xv[j].x);
            acc.y += vv * bf2f(xv[j].y);
            acc.z += vv * bf2f(xv[j].z);
            acc.w += vv * bf2f(xv[j].w);
        }
    }
    for (; i < e; ++i) {
        int2 cv = ebuf[i];
        int rl = (cv.x >> 17) & (BROW - 1);
        if (rl != cur) {
            if (cur >= 0)
                *(float4*)&out[(size_t)(row0 + cur) * N_OUT_CH + l16 * 4] = acc;
            cur = rl;
            acc = make_float4(0.f, 0.f, 0.f, 0.f);
        }
        ushort4 xv = *(const ushort4*)&Xp[(size_t)(cv.x & 0x1FFFF) * N_OUT_CH + l16 * 4];
        float vv = __int_as_float(cv.y);
        acc.x += vv * bf2f(xv.x);
        acc.y += vv * bf2f(xv.y);
        acc.z += vv * bf2f(xv.z);
        acc.w += vv * bf2f(xv.w);
    }
    if (cur >= 0)
        *(float4*)&out[(size_t)(row0 + cur) * N_OUT_CH + l16 * 4] = acc;

    // zero-fill this quarter's empty rows (rare: P ~ e^-16 per row)
    #pragma unroll
    for (int r = 0; r < 4; ++r) {
        int lr = qr0 + r;
        if (rb[lr] == rb[lr + 1]) {
            int gr = row0 + lr;
            if (gr < nrows)
                *(float4*)&out[(size_t)gr * N_OUT_CH + l16 * 4] =
                    make_float4(0.f, 0.f, 0.f, 0.f);
        }
    }

    // overflow tail: normally n==0 -> one broadcast load + exit
    __syncthreads();
    const int lane = t & 63;
    int n = min(ovfcnt[0], OVFCAP);
    for (int e2 = wave; e2 < n; e2 += 8) {
        int4 v = ovf[e2];
        if ((v.x >> 7) == b)
            atomicAdd(&out[(size_t)v.x * N_OUT_CH + lane],
                      __int_as_float(v.z) * bf2f(Xp[(size_t)v.y * N_OUT_CH + lane]));
    }
}

// --- Fallback atomic SpMM (ws too small — not expected) ---
__global__ __launch_bounds__(256) void spmm_atomic_kernel(const int* __restrict__ rows,
        const int* __restrict__ cols, const float* __restrict__ vals,
        const ushort* __restrict__ Xp, float* __restrict__ out, int nnz) {
    int t = blockIdx.x * blockDim.x + threadIdx.x;
    int e = t >> 6;
    int c = t & 63;
    if (e < nnz) {
        atomicAdd(&out[(size_t)rows[e] * N_OUT_CH + c],
                  vals[e] * bf2f(Xp[(size_t)cols[e] * N_OUT_CH + c]));
    }
}

extern "C" void kernel_launch(void* const* d_in, const int* in_sizes, int n_in,
                              void* d_out, int out_size, void* d_ws, size_t ws_size,
                              hipStream_t stream) {
    const float* X      = (const float*)d_in[2];
    const float* W      = (const float*)d_in[3];
    const int*   L_rows = (const int*)d_in[4];
    const int*   L_cols = (const int*)d_in[5];
    const float* L_vals = (const float*)d_in[6];
    float* out = (float*)d_out;

    const int nrows = in_sizes[2] / N_IN_CH;   // 100000
    const int nnz   = in_sizes[4];             // 1600000
    const int nb    = (nrows + BROW - 1) / BROW;   // 782 buckets

    // workspace layout (16B-aligned blocks)
    size_t off_xp  = 0;
    size_t xp_b    = (size_t)nrows * N_OUT_CH * 2;                   // Xp bf16: 12.8 MB
    size_t off_bc  = off_xp + ((xp_b + 15) & ~(size_t)15);           // bcur[nb] + ovfcnt
    size_t off_ov  = off_bc + (((size_t)(nb + 1) * 4 + 15) & ~(size_t)15);  // ovf int4
    size_t off_cv  = off_ov + (size_t)OVFCAP * 16;                   // colbuf padded
    size_t need    = off_cv + (size_t)nb * ECAP * 8;                 // 25.6 MB

    ushort* Xp = (ushort*)((char*)d_ws + off_xp);
    const bool binned = (ws_size >= need && nb <= NBK);
    int* bcur = (int*)((char*)d_ws + off_bc);

    int ntiles = (nrows + 15) >> 4;
    int ngemm = NGEMM;
    int maxg = (ntiles + 3) / 4;
    if (ngemm > maxg) ngemm = maxg;

    if (binned) {
        int*  ovfcnt = bcur + nb;                          // 1 int
        int4* ovf    = (int4*)((char*)d_ws + off_ov);
        int2* colbuf = (int2*)((char*)d_ws + off_cv);
        int nbin = (nnz + B1_E - 1) / B1_E;

        hipMemsetAsync(bcur, 0, (size_t)(nb + 1) * 4, stream);
        fused_kernel<<<ngemm + nbin, 256, 0, stream>>>(X, W, Xp, nrows, ngemm,
                L_rows, L_cols, L_vals, bcur, ovfcnt, ovf, colbuf, nnz, nb);
        bspmm_kernel<<<nb, 512, 0, stream>>>(bcur, colbuf, Xp, out, nrows, ovfcnt, ovf);
    } else {
        fused_kernel<<<ngemm, 256, 0, stream>>>(X, W, Xp, nrows, ngemm,
                nullptr, nullptr, nullptr, nullptr, nullptr, nullptr, nullptr, 0, 0);
        hipMemsetAsync(d_out, 0, (size_t)out_size * sizeof(float), stream);
        long long total = (long long)nnz * 64;
        spmm_atomic_kernel<<<(int)((total + 255) / 256), 256, 0, stream>>>(
            L_rows, L_cols, L_vals, Xp, out, nnz);
    }
}